// Round 13
// baseline (84.804 us; speedup 1.0000x reference)
//
#include <hip/hip_runtime.h>
#include <cstdint>
#include <cstddef>

// IMUCNN1DEncoder — round 13: r12 + r3-proven LDS bank scheme: pow2 row strides
// (act1 128B, act2 256B, pools 512B) with 16B-unit XOR swizzle (u ^= row&7) on
// BOTH write and read sides. r3 measured 0 bank conflicts with this scheme vs the
// constant ~6M of the padded-stride rounds. All else identical to r12 (78.8 us).
// K0:    weight prep (BN fold -> bf16 per-lane fragment panels in d_ws)
// K_all: imu->LDS (per-wave) -> conv1 MFMA (reg im2col) -> act1 LDS -> conv2 16x16
//        (W=A full-prefetch regs, act=B LDS) -> act2 LDS -> conv3 16x16 SWAPPED
//        (2-deep W prefetch) -> pool (hi/lo planes) -> linear (full prefetch) -> out.

namespace {

typedef __attribute__((ext_vector_type(8))) short short8;   // 8 bf16 = 4 VGPR
typedef __attribute__((ext_vector_type(4))) float f32x4;

constexpr int NSEG = 32 * 512;          // 16384
constexpr float kEps = 1e-5f;

// d_ws layout (bytes)
constexpr size_t OFF_A2F = 0;            // 3072 frags  * 16 = 49,152
constexpr size_t OFF_A3F = 49152;        // 12288 frags * 16 = 196,608
constexpr size_t OFF_WP  = 245760;       // 8192 frags  * 16 = 131,072
constexpr size_t OFF_B2  = 376832;       // 512
constexpr size_t OFF_B3  = 377344;       // 1024
constexpr size_t OFF_A1F = 378368;       // 256 frags * 16 = 4,096
constexpr size_t OFF_B1C = 382464;       // 256
constexpr size_t WS_NEED = 382720;

// LDS layout (static, 63,488 B -> 2 blocks/CU)
constexpr int L_ACT2 = 18432;    // act1: 8 segs * 18 rows * 128 B = 18,432
constexpr int L_POOL = 55296;    // act2: 8 * 18 * 256 B = 36,864
constexpr int L_TOTAL = 63488;   // pools: 16 rows * 512 B = 8,192 (imu overlays)

__device__ __forceinline__ unsigned short f2bf(float f) {    // prep path only
    union { float f; unsigned int u; } a; a.f = f;
    unsigned int u = a.u + 0x7FFFu + ((a.u >> 16) & 1u);     // RNE
    return (unsigned short)(u >> 16);
}

__device__ __forceinline__ unsigned int cvt_pk_bf16(float a, float b) {
    unsigned int r;                                           // lo16=bf(a), hi16=bf(b)
    asm("v_cvt_pk_bf16_f32 %0, %1, %2" : "=v"(r) : "v"(a), "v"(b));
    return r;
}
__device__ __forceinline__ float asf(unsigned int u) {
    union { unsigned int u; float f; } a; a.u = u; return a.f;
}

__device__ __forceinline__ void gll16(const void* g, void* l) {
    __builtin_amdgcn_global_load_lds(
        (const __attribute__((address_space(1))) unsigned int*)g,
        (__attribute__((address_space(3))) unsigned int*)l, 16, 0, 0);
}

__device__ __forceinline__ short8 frag16(const void* p) {
    return __builtin_bit_cast(short8, *(const int4*)p);
}

// raw barrier: drain LDS ops only; vmcnt (VGPR prefetches) survives.
__device__ __forceinline__ void sync_lds() {
    asm volatile("s_waitcnt lgkmcnt(0)" ::: "memory");
    __builtin_amdgcn_s_barrier();
    asm volatile("" ::: "memory");
    __builtin_amdgcn_sched_barrier(0);
}

__device__ __forceinline__ float leaky(float y) { return fmaxf(y, 0.1f * y); }

// ---------------------------------------------------------------- K0: prep
// idx: A2F 3072 | A3F 12288 | WP 8192 | b2 128 | b3 256 | A1F 256 | b1c 64 = 24,256
__global__ __launch_bounds__(256) void k0_prep(
    const float* __restrict__ w1, const float* __restrict__ b1, const float* __restrict__ g1,
    const float* __restrict__ be1, const float* __restrict__ m1, const float* __restrict__ v1,
    const float* __restrict__ w2, const float* __restrict__ b2, const float* __restrict__ g2,
    const float* __restrict__ be2, const float* __restrict__ m2, const float* __restrict__ v2,
    const float* __restrict__ w3, const float* __restrict__ b3, const float* __restrict__ g3,
    const float* __restrict__ be3, const float* __restrict__ m3, const float* __restrict__ v3,
    const float* __restrict__ wp, char* __restrict__ ws)
{
    int idx = blockIdx.x * 256 + threadIdx.x;
    if (idx < 3072) {                       // A2F frag f=(kstep s[6], rtile[8])
        int f = idx >> 6, lane = idx & 63;
        int tap = f >> 4, qq = (f >> 3) & 1, rtile = f & 7;
        int row = rtile * 16 + (lane & 15);
        int kb = qq * 32 + (lane >> 4) * 8;
        float a = g2[row] * rsqrtf(v2[row] + kEps);
        unsigned short us[8];
#pragma unroll
        for (int j = 0; j < 8; ++j)
            us[j] = f2bf(a * w2[row * 192 + (kb + j) * 3 + tap]);
        *(int4*)(ws + OFF_A2F + (size_t)idx * 16) = *(const int4*)us;
    } else if (idx < 15360) {               // A3F frag f=(kstep s[12], ntile[16])
        int u = idx - 3072;
        int f = u >> 6, lane = u & 63;
        int ks = f >> 5, qq = (f >> 4) & 1, rtile = f & 15;
        int tap = ks >> 1, ih = ks & 1;
        int row = rtile * 16 + (lane & 15);
        int kb = qq * 32 + (lane >> 4) * 8;
        float a = g3[row] * rsqrtf(v3[row] + kEps);
        unsigned short us[8];
#pragma unroll
        for (int j = 0; j < 8; ++j) {
            int i = ih * 64 + kb + j;
            us[j] = f2bf(a * w3[row * 384 + i * 3 + tap]);
        }
        *(int4*)(ws + OFF_A3F + (size_t)u * 16) = *(const int4*)us;
    } else if (idx < 23552) {               // WP frags, scaled 1/16
        int u = idx - 15360;
        int f = u >> 6, lane = u & 63;
        int o = (f >> 3) * 16 + (lane & 15);
        int cb = (f & 7) * 32 + (lane >> 4) * 8;
        unsigned short us[8];
#pragma unroll
        for (int j = 0; j < 8; ++j)
            us[j] = f2bf(wp[o * 256 + cb + j] * 0.0625f);
        *(int4*)(ws + OFF_WP + (size_t)u * 16) = *(const int4*)us;
    } else if (idx < 23680) {
        int o = idx - 23552;
        float a = g2[o] * rsqrtf(v2[o] + kEps);
        ((float*)(ws + OFF_B2))[o] = a * (b2[o] - m2[o]) + be2[o];
    } else if (idx < 23936) {
        int o = idx - 23680;
        float a = g3[o] * rsqrtf(v3[o] + kEps);
        ((float*)(ws + OFF_B3))[o] = a * (b3[o] - m3[o]) + be3[o];
    } else if (idx < 24192) {               // A1F frag f=mtile[4]; K=18 padded to 32
        int u = idx - 23936;
        int f = u >> 6, lane = u & 63;
        int row = f * 16 + (lane & 15);
        float a = g1[row] * rsqrtf(v1[row] + kEps);
        unsigned short us[8];
#pragma unroll
        for (int j = 0; j < 8; ++j) {
            int k = (lane >> 4) * 8 + j;
            us[j] = (k < 18) ? f2bf(a * w1[row * 18 + k]) : (unsigned short)0;
        }
        *(int4*)(ws + OFF_A1F + (size_t)u * 16) = *(const int4*)us;
    } else if (idx < 24256) {               // bias1'
        int o = idx - 24192;
        float a = g1[o] * rsqrtf(v1[o] + kEps);
        ((float*)(ws + OFF_B1C))[o] = a * (b1[o] - m1[o]) + be1[o];
    }
}

// ---------------------------------------------------------------- K_all
__global__ __launch_bounds__(512, 4) void k_all(
    const float* __restrict__ imu,
    const char* __restrict__ ws, const float* __restrict__ bp,
    float* __restrict__ out)
{
    __shared__ char smem[L_TOTAL];
    char* act1L  = smem;
    char* act2L  = smem + L_ACT2;
    char* poolsL = smem + L_POOL;
    char* imuL   = poolsL;                     // 3 KB f32 imu, dead after conv1
    const char* A2F = ws + OFF_A2F;
    const char* A3F = ws + OFF_A3F;
    const char* WPF = ws + OFF_WP;
    const float* bias2 = (const float*)(ws + OFF_B2);
    const float* bias3 = (const float*)(ws + OFF_B3);

    const int tid = threadIdx.x, lane = tid & 63, wid = tid >> 6;  // wid 0..7
    const int lo = lane & 15, hi = lane >> 4;
    const int seg0 = blockIdx.x * 8;

    // ---- conv1 weight/bias prefetch (latency overlaps imu staging)
    short8 a1p[4];
#pragma unroll
    for (int m = 0; m < 4; ++m)
        a1p[m] = frag16(ws + OFF_A1F + (size_t)(m * 64 + lane) * 16);
    float4 bb4[4];
#pragma unroll
    for (int m = 0; m < 4; ++m)
        bb4[m] = *(const float4*)((const float*)(ws + OFF_B1C) + m * 16 + hi * 4);

    // ---- phase 0: per-wave imu staging (wave w stages seg0+w's 384 B); no barrier
    if (lane < 24)
        gll16((const char*)imu + (size_t)(seg0 + wid) * 384 + lane * 16,
              imuL + wid * 384);
    asm volatile("s_waitcnt vmcnt(0)" ::: "memory");
    __builtin_amdgcn_sched_barrier(0);

    // ---- phase 1: conv1 via MFMA; im2col B-fragment built directly in registers.
    {
        const float* xb = (const float*)(imuL + wid * 384) + lo * 6;
        float v[8];
        if (hi == 0) {          // k=0..7: (i,t)=(0,0)(0,1)(0,2)(1,0)(1,1)(1,2)(2,0)(2,1)
            v[0] = lo > 0  ? xb[-6] : 0.f;
            v[1] = xb[0];
            v[2] = lo < 15 ? xb[6]  : 0.f;
            v[3] = lo > 0  ? xb[-5] : 0.f;
            v[4] = xb[1];
            v[5] = lo < 15 ? xb[7]  : 0.f;
            v[6] = lo > 0  ? xb[-4] : 0.f;
            v[7] = xb[2];
        } else if (hi == 1) {   // k=8..15: (2,2)(3,0)(3,1)(3,2)(4,0)(4,1)(4,2)(5,0)
            v[0] = lo < 15 ? xb[8]  : 0.f;
            v[1] = lo > 0  ? xb[-3] : 0.f;
            v[2] = xb[3];
            v[3] = lo < 15 ? xb[9]  : 0.f;
            v[4] = lo > 0  ? xb[-2] : 0.f;
            v[5] = xb[4];
            v[6] = lo < 15 ? xb[10] : 0.f;
            v[7] = lo > 0  ? xb[-1] : 0.f;
        } else if (hi == 2) {   // k=16,17: (5,1)(5,2); rest pad
            v[0] = xb[5];
            v[1] = lo < 15 ? xb[11] : 0.f;
            v[2] = v[3] = v[4] = v[5] = v[6] = v[7] = 0.f;
        } else {
            v[0] = v[1] = v[2] = v[3] = v[4] = v[5] = v[6] = v[7] = 0.f;
        }
        uint4 pkv;
        pkv.x = cvt_pk_bf16(v[0], v[1]);
        pkv.y = cvt_pk_bf16(v[2], v[3]);
        pkv.z = cvt_pk_bf16(v[4], v[5]);
        pkv.w = cvt_pk_bf16(v[6], v[7]);
        short8 bq = __builtin_bit_cast(short8, pkv);

        f32x4 acc1[4];
#pragma unroll
        for (int m = 0; m < 4; ++m) acc1[m] = f32x4{0.f, 0.f, 0.f, 0.f};
#pragma unroll
        for (int m = 0; m < 4; ++m)
            acc1[m] = __builtin_amdgcn_mfma_f32_16x16x32_bf16(a1p[m], bq, acc1[m], 0, 0, 0);
        // epilogue: bias + leaky -> bf16 -> act1 (row=(seg,l), col=cout), swizzled
        {
            const int row = wid * 18 + lo + 1;
#pragma unroll
            for (int m = 0; m < 4; ++m) {
                float y0 = leaky(acc1[m][0] + bb4[m].x);
                float y1 = leaky(acc1[m][1] + bb4[m].y);
                float y2 = leaky(acc1[m][2] + bb4[m].z);
                float y3 = leaky(acc1[m][3] + bb4[m].w);
                uint2 pk;
                pk.x = cvt_pk_bf16(y0, y1);
                pk.y = cvt_pk_bf16(y2, y3);
                int u = m * 2 + (hi >> 1);
                *(uint2*)(act1L + row * 128 + ((u ^ (row & 7)) << 4) + (hi & 1) * 8) = pk;
            }
        }
        // zero act1 halo rows (8 segs x 2 rows x 8 units = 128)
        if (tid < 128) {
            int s = tid >> 4, rest = tid & 15;
            int h = rest >> 3, unit = rest & 7;
            int4 z; z.x = z.y = z.z = z.w = 0;
            *(int4*)(act1L + (s * 18 + h * 17) * 128 + unit * 16) = z;
        }
        // zero act2 halo rows (8 x 2 x 16 = 256)
        if (tid < 256) {
            int s = tid >> 5, rest = tid & 31;
            int h = rest >> 4, unit = rest & 15;
            int4 z; z.x = z.y = z.z = z.w = 0;
            *(int4*)(act2L + (s * 18 + h * 17) * 256 + unit * 16) = z;
        }
    }

    // ---- conv2 FULL weight prefetch (12 frags = 48 VGPR) BEFORE B1
    const int mi2 = wid >> 1, ni2 = wid & 1;
    short8 a2p[6][2];
#pragma unroll
    for (int s = 0; s < 6; ++s)
#pragma unroll
        for (int rt = 0; rt < 2; ++rt)
            a2p[s][rt] = frag16(A2F + (size_t)((s * 8 + mi2 * 2 + rt) * 64 + lane) * 16);

    sync_lds();                                // B1: act1 ready

    // ---- phase 2: conv2 16x16 (W as A regs, act1 as B LDS, swizzled reads)
    f32x4 acc2[2][4];
#pragma unroll
    for (int i = 0; i < 2; ++i)
#pragma unroll
        for (int j = 0; j < 4; ++j) acc2[i][j] = f32x4{0.f, 0.f, 0.f, 0.f};
    {
#pragma unroll
        for (int s = 0; s < 6; ++s) {
            const int tap = s >> 1, qq = s & 1;
            short8 bfr[4];
#pragma unroll
            for (int ct = 0; ct < 4; ++ct) {
                int row = (ni2 * 4 + ct) * 18 + lo + tap;
                int u = qq * 4 + hi;
                bfr[ct] = frag16(act1L + row * 128 + ((u ^ (row & 7)) << 4));
            }
#pragma unroll
            for (int ct = 0; ct < 4; ++ct) {
                acc2[0][ct] = __builtin_amdgcn_mfma_f32_16x16x32_bf16(a2p[s][0], bfr[ct], acc2[0][ct], 0, 0, 0);
                acc2[1][ct] = __builtin_amdgcn_mfma_f32_16x16x32_bf16(a2p[s][1], bfr[ct], acc2[1][ct], 0, 0, 0);
            }
        }
    }

    // ---- conv3 weight+bias prefetch (s=0,1) issued BEFORE B2
    const int ni3 = wid >> 1, mi3 = wid & 1;
    short8 w3p[2][4];
#pragma unroll
    for (int s = 0; s < 2; ++s)
#pragma unroll
        for (int ct = 0; ct < 4; ++ct)
            w3p[s][ct] = frag16(A3F + (size_t)((s * 16 + ni3 * 4 + ct) * 64 + lane) * 16);
    float b3r[4];
#pragma unroll
    for (int ct = 0; ct < 4; ++ct)
        b3r[ct] = bias3[(ni3 * 4 + ct) * 16 + lo];

    // conv2 epilogue: bias + leaky -> bf16 -> act2 LDS (row=(seg,l), col=cout), swizzled
#pragma unroll
    for (int rt = 0; rt < 2; ++rt) {
        int ch0 = (mi2 * 2 + rt) * 16 + hi * 4;
        float4 b4 = *(const float4*)(bias2 + ch0);
#pragma unroll
        for (int ct = 0; ct < 4; ++ct) {
            float y0 = leaky(acc2[rt][ct][0] + b4.x);
            float y1 = leaky(acc2[rt][ct][1] + b4.y);
            float y2 = leaky(acc2[rt][ct][2] + b4.z);
            float y3 = leaky(acc2[rt][ct][3] + b4.w);
            uint2 pk;
            pk.x = cvt_pk_bf16(y0, y1);
            pk.y = cvt_pk_bf16(y2, y3);
            int row = (ni2 * 4 + ct) * 18 + lo + 1;
            int u = (mi2 * 2 + rt) * 2 + (hi >> 1);
            *(uint2*)(act2L + row * 256 + ((u ^ (row & 7)) << 4) + (hi & 1) * 8) = pk;
        }
    }
    sync_lds();                                // B2: act2 ready

    // ---- phase 3: conv3 16x16 SWAPPED (act2 as A LDS swizzled, W as B 2-deep regs)
    f32x4 acc3[4][4];                          // [mt][ct]
#pragma unroll
    for (int i = 0; i < 4; ++i)
#pragma unroll
        for (int j = 0; j < 4; ++j) acc3[i][j] = f32x4{0.f, 0.f, 0.f, 0.f};
    {
#pragma unroll
        for (int s = 0; s < 12; ++s) {
            const int tap = s >> 2, ih = (s >> 1) & 1, qq = s & 1;
            short8 afr[4];
#pragma unroll
            for (int mt = 0; mt < 4; ++mt) {
                int row = (mi3 * 4 + mt) * 18 + lo + tap;
                int u = ih * 8 + qq * 4 + hi;
                afr[mt] = frag16(act2L + row * 256 + ((u ^ (row & 7)) << 4));
            }
#pragma unroll
            for (int mt = 0; mt < 4; ++mt)
#pragma unroll
                for (int ct = 0; ct < 4; ++ct)
                    acc3[mt][ct] = __builtin_amdgcn_mfma_f32_16x16x32_bf16(
                        afr[mt], w3p[s & 1][ct], acc3[mt][ct], 0, 0, 0);
            if (s < 10) {
#pragma unroll
                for (int ct = 0; ct < 4; ++ct)
                    w3p[s & 1][ct] = frag16(A3F + (size_t)(((s + 2) * 16 + ni3 * 4 + ct) * 64 + lane) * 16);
            }
        }
    }

    // ---- phase 4: pool. C: row = l (hi*4+r), col = cout (lo). hi/lo bf16 planes.
#pragma unroll
    for (int ct = 0; ct < 4; ++ct) {
        int co = (ni3 * 4 + ct) * 16 + lo;
        float bv = b3r[ct];
        float t[4];
#pragma unroll
        for (int mt = 0; mt < 4; ++mt) {
            float s4 = 0.f;
#pragma unroll
            for (int r = 0; r < 4; ++r)
                s4 += leaky(acc3[mt][ct][r] + bv);
            s4 += __shfl_xor(s4, 16, 64);
            s4 += __shfl_xor(s4, 32, 64);
            t[mt] = s4;
        }
        unsigned int pkA = cvt_pk_bf16(t[0], t[1]);
        unsigned int pkB = cvt_pk_bf16(t[2], t[3]);
        float r0 = t[0] - asf(pkA << 16);
        float r1 = t[1] - asf(pkA & 0xffff0000u);
        float r2 = t[2] - asf(pkB << 16);
        float r3 = t[3] - asf(pkB & 0xffff0000u);
        unsigned int pkrA = cvt_pk_bf16(r0, r1);
        unsigned int pkrB = cvt_pk_bf16(r2, r3);
        if (hi == 0) {
            const int row0 = mi3 * 4;
            const int ub = (ni3 * 4 + ct) * 2 + (lo >> 3);
            const int sub = (lo & 7) * 2;
            unsigned short vals[8] = {
                (unsigned short)pkA,  (unsigned short)(pkA >> 16),
                (unsigned short)pkB,  (unsigned short)(pkB >> 16),
                (unsigned short)pkrA, (unsigned short)(pkrA >> 16),
                (unsigned short)pkrB, (unsigned short)(pkrB >> 16)};
#pragma unroll
            for (int k = 0; k < 8; ++k) {
                int rowN = row0 + (k & 3) + (k >> 2) * 8;
                *(unsigned short*)(poolsL + rowN * 512 + ((ub ^ (rowN & 7)) << 4) + sub) = vals[k];
            }
        }
    }

    // ---- linear FULL weight+bias prefetch (16 frags; acc3 dead now)
    short8 wbp[8][2];
#pragma unroll
    for (int q = 0; q < 8; ++q)
#pragma unroll
        for (int ct = 0; ct < 2; ++ct)
            wbp[q][ct] = frag16(WPF + (size_t)(((wid * 2 + ct) * 8 + q) * 64 + lane) * 16);
    float bpr[2];
#pragma unroll
    for (int ct = 0; ct < 2; ++ct)
        bpr[ct] = bp[(wid * 2 + ct) * 16 + lo];

    sync_lds();                                // B3: pools ready

    // ---- phase 5: linear (pools rows 0-7 hi, 8-15 lo as A, swizzled; WP as B).
    {
        f32x4 acc4[2];
        acc4[0] = f32x4{0.f, 0.f, 0.f, 0.f};
        acc4[1] = f32x4{0.f, 0.f, 0.f, 0.f};
#pragma unroll
        for (int q = 0; q < 8; ++q) {
            int u = q * 4 + hi;
            short8 pa = frag16(poolsL + lo * 512 + ((u ^ (lo & 7)) << 4));
            acc4[0] = __builtin_amdgcn_mfma_f32_16x16x32_bf16(pa, wbp[q][0], acc4[0], 0, 0, 0);
            acc4[1] = __builtin_amdgcn_mfma_f32_16x16x32_bf16(pa, wbp[q][1], acc4[1], 0, 0, 0);
        }
#pragma unroll
        for (int ct = 0; ct < 2; ++ct) {
            int o = (wid * 2 + ct) * 16 + lo;
            float bv = bpr[ct];
#pragma unroll
            for (int r = 0; r < 4; ++r) {
                float t = acc4[ct][r] + __shfl_xor(acc4[ct][r], 32, 64);
                if (hi < 2)
                    out[(size_t)(seg0 + hi * 4 + r) * 256 + o] = t + bv;
            }
        }
    }
}

}  // namespace

extern "C" void kernel_launch(void* const* d_in, const int* in_sizes, int n_in,
                              void* d_out, int out_size, void* d_ws, size_t ws_size,
                              hipStream_t stream) {
    if (ws_size < WS_NEED) return;

    const float* imu = (const float*)d_in[0];
    const float* w1 = (const float*)d_in[1];  const float* b1 = (const float*)d_in[2];
    const float* g1 = (const float*)d_in[3];  const float* be1 = (const float*)d_in[4];
    const float* m1 = (const float*)d_in[5];  const float* v1 = (const float*)d_in[6];
    const float* w2 = (const float*)d_in[7];  const float* b2 = (const float*)d_in[8];
    const float* g2 = (const float*)d_in[9];  const float* be2 = (const float*)d_in[10];
    const float* m2 = (const float*)d_in[11]; const float* v2 = (const float*)d_in[12];
    const float* w3 = (const float*)d_in[13]; const float* b3 = (const float*)d_in[14];
    const float* g3 = (const float*)d_in[15]; const float* be3 = (const float*)d_in[16];
    const float* m3 = (const float*)d_in[17]; const float* v3 = (const float*)d_in[18];
    const float* wp = (const float*)d_in[19]; const float* bp = (const float*)d_in[20];
    float* out = (float*)d_out;
    char* ws = (char*)d_ws;

    hipLaunchKernelGGL(k0_prep, dim3(95), dim3(256), 0, stream,
                       w1, b1, g1, be1, m1, v1,
                       w2, b2, g2, be2, m2, v2, w3, b3, g3, be3, m3, v3, wp, ws);
    hipLaunchKernelGGL(k_all, dim3(NSEG / 8), dim3(512), 0, stream,
                       imu, ws, bp, out);
}

// Round 14
// 78.612 us; speedup vs baseline: 1.0788x; 1.0788x over previous
//
#include <hip/hip_runtime.h>
#include <cstdint>
#include <cstddef>

// IMUCNN1DEncoder — round 14: clean revert to round 12 (78.8 us best).
// r13's pow2+XOR LDS scheme regressed (scratch spill in pool scatter: WRITE_SIZE
// 19->59 MB; conflicts only -26%). Padded strides restored.
// K0:    weight prep (BN fold -> bf16 per-lane fragment panels in d_ws)
// K_all: imu->LDS (per-wave) -> conv1 MFMA (reg im2col) -> act1 LDS -> conv2 16x16
//        (W=A full-prefetch regs, act=B LDS) -> act2 LDS -> conv3 16x16 SWAPPED
//        (2-deep W prefetch) -> pool (hi/lo planes) -> linear (full prefetch) -> out.

namespace {

typedef __attribute__((ext_vector_type(8))) short short8;   // 8 bf16 = 4 VGPR
typedef __attribute__((ext_vector_type(4))) float f32x4;

constexpr int NSEG = 32 * 512;          // 16384
constexpr float kEps = 1e-5f;

// d_ws layout (bytes)
constexpr size_t OFF_A2F = 0;            // 3072 frags  * 16 = 49,152
constexpr size_t OFF_A3F = 49152;        // 12288 frags * 16 = 196,608
constexpr size_t OFF_WP  = 245760;       // 8192 frags  * 16 = 131,072
constexpr size_t OFF_B2  = 376832;       // 512
constexpr size_t OFF_B3  = 377344;       // 1024
constexpr size_t OFF_A1F = 378368;       // 256 frags * 16 = 4,096
constexpr size_t OFF_B1C = 382464;       // 256
constexpr size_t WS_NEED = 382720;

// LDS layout (static, 68,352 B -> 2 blocks/CU at 160KB)
constexpr int L_ACT2 = 20736;    // act1: 8 segs * 18 rows * 144 B = 20,736
constexpr int L_POOL = 59904;    // act2: 8 * 18 * 272 B = 39,168
constexpr int L_TOTAL = 68352;   // pools: 16 rows * 528 B = 8,448 (imu overlays)

__device__ __forceinline__ unsigned short f2bf(float f) {    // prep path only
    union { float f; unsigned int u; } a; a.f = f;
    unsigned int u = a.u + 0x7FFFu + ((a.u >> 16) & 1u);     // RNE
    return (unsigned short)(u >> 16);
}

__device__ __forceinline__ unsigned int cvt_pk_bf16(float a, float b) {
    unsigned int r;                                           // lo16=bf(a), hi16=bf(b)
    asm("v_cvt_pk_bf16_f32 %0, %1, %2" : "=v"(r) : "v"(a), "v"(b));
    return r;
}
__device__ __forceinline__ float asf(unsigned int u) {
    union { unsigned int u; float f; } a; a.u = u; return a.f;
}

__device__ __forceinline__ void gll16(const void* g, void* l) {
    __builtin_amdgcn_global_load_lds(
        (const __attribute__((address_space(1))) unsigned int*)g,
        (__attribute__((address_space(3))) unsigned int*)l, 16, 0, 0);
}

__device__ __forceinline__ short8 frag16(const void* p) {
    return __builtin_bit_cast(short8, *(const int4*)p);
}

// raw barrier: drain LDS ops only; vmcnt (VGPR prefetches) survives.
__device__ __forceinline__ void sync_lds() {
    asm volatile("s_waitcnt lgkmcnt(0)" ::: "memory");
    __builtin_amdgcn_s_barrier();
    asm volatile("" ::: "memory");
    __builtin_amdgcn_sched_barrier(0);
}

__device__ __forceinline__ float leaky(float y) { return fmaxf(y, 0.1f * y); }

// ---------------------------------------------------------------- K0: prep
// idx: A2F 3072 | A3F 12288 | WP 8192 | b2 128 | b3 256 | A1F 256 | b1c 64 = 24,256
__global__ __launch_bounds__(256) void k0_prep(
    const float* __restrict__ w1, const float* __restrict__ b1, const float* __restrict__ g1,
    const float* __restrict__ be1, const float* __restrict__ m1, const float* __restrict__ v1,
    const float* __restrict__ w2, const float* __restrict__ b2, const float* __restrict__ g2,
    const float* __restrict__ be2, const float* __restrict__ m2, const float* __restrict__ v2,
    const float* __restrict__ w3, const float* __restrict__ b3, const float* __restrict__ g3,
    const float* __restrict__ be3, const float* __restrict__ m3, const float* __restrict__ v3,
    const float* __restrict__ wp, char* __restrict__ ws)
{
    int idx = blockIdx.x * 256 + threadIdx.x;
    if (idx < 3072) {                       // A2F frag f=(kstep s[6], rtile[8])
        int f = idx >> 6, lane = idx & 63;
        int tap = f >> 4, qq = (f >> 3) & 1, rtile = f & 7;
        int row = rtile * 16 + (lane & 15);
        int kb = qq * 32 + (lane >> 4) * 8;
        float a = g2[row] * rsqrtf(v2[row] + kEps);
        unsigned short us[8];
#pragma unroll
        for (int j = 0; j < 8; ++j)
            us[j] = f2bf(a * w2[row * 192 + (kb + j) * 3 + tap]);
        *(int4*)(ws + OFF_A2F + (size_t)idx * 16) = *(const int4*)us;
    } else if (idx < 15360) {               // A3F frag f=(kstep s[12], ntile[16])
        int u = idx - 3072;
        int f = u >> 6, lane = u & 63;
        int ks = f >> 5, qq = (f >> 4) & 1, rtile = f & 15;
        int tap = ks >> 1, ih = ks & 1;
        int row = rtile * 16 + (lane & 15);
        int kb = qq * 32 + (lane >> 4) * 8;
        float a = g3[row] * rsqrtf(v3[row] + kEps);
        unsigned short us[8];
#pragma unroll
        for (int j = 0; j < 8; ++j) {
            int i = ih * 64 + kb + j;
            us[j] = f2bf(a * w3[row * 384 + i * 3 + tap]);
        }
        *(int4*)(ws + OFF_A3F + (size_t)u * 16) = *(const int4*)us;
    } else if (idx < 23552) {               // WP frags, scaled 1/16
        int u = idx - 15360;
        int f = u >> 6, lane = u & 63;
        int o = (f >> 3) * 16 + (lane & 15);
        int cb = (f & 7) * 32 + (lane >> 4) * 8;
        unsigned short us[8];
#pragma unroll
        for (int j = 0; j < 8; ++j)
            us[j] = f2bf(wp[o * 256 + cb + j] * 0.0625f);
        *(int4*)(ws + OFF_WP + (size_t)u * 16) = *(const int4*)us;
    } else if (idx < 23680) {
        int o = idx - 23552;
        float a = g2[o] * rsqrtf(v2[o] + kEps);
        ((float*)(ws + OFF_B2))[o] = a * (b2[o] - m2[o]) + be2[o];
    } else if (idx < 23936) {
        int o = idx - 23680;
        float a = g3[o] * rsqrtf(v3[o] + kEps);
        ((float*)(ws + OFF_B3))[o] = a * (b3[o] - m3[o]) + be3[o];
    } else if (idx < 24192) {               // A1F frag f=mtile[4]; K=18 padded to 32
        int u = idx - 23936;
        int f = u >> 6, lane = u & 63;
        int row = f * 16 + (lane & 15);
        float a = g1[row] * rsqrtf(v1[row] + kEps);
        unsigned short us[8];
#pragma unroll
        for (int j = 0; j < 8; ++j) {
            int k = (lane >> 4) * 8 + j;
            us[j] = (k < 18) ? f2bf(a * w1[row * 18 + k]) : (unsigned short)0;
        }
        *(int4*)(ws + OFF_A1F + (size_t)u * 16) = *(const int4*)us;
    } else if (idx < 24256) {               // bias1'
        int o = idx - 24192;
        float a = g1[o] * rsqrtf(v1[o] + kEps);
        ((float*)(ws + OFF_B1C))[o] = a * (b1[o] - m1[o]) + be1[o];
    }
}

// ---------------------------------------------------------------- K_all
__global__ __launch_bounds__(512, 4) void k_all(
    const float* __restrict__ imu,
    const char* __restrict__ ws, const float* __restrict__ bp,
    float* __restrict__ out)
{
    __shared__ char smem[L_TOTAL];
    char* act1L  = smem;
    char* act2L  = smem + L_ACT2;
    char* poolsL = smem + L_POOL;
    char* imuL   = poolsL;                     // 3 KB f32 imu, dead after conv1
    const char* A2F = ws + OFF_A2F;
    const char* A3F = ws + OFF_A3F;
    const char* WPF = ws + OFF_WP;
    const float* bias2 = (const float*)(ws + OFF_B2);
    const float* bias3 = (const float*)(ws + OFF_B3);

    const int tid = threadIdx.x, lane = tid & 63, wid = tid >> 6;  // wid 0..7
    const int lo = lane & 15, hi = lane >> 4;
    const int seg0 = blockIdx.x * 8;

    // ---- conv1 weight/bias prefetch (latency overlaps imu staging)
    short8 a1p[4];
#pragma unroll
    for (int m = 0; m < 4; ++m)
        a1p[m] = frag16(ws + OFF_A1F + (size_t)(m * 64 + lane) * 16);
    float4 bb4[4];
#pragma unroll
    for (int m = 0; m < 4; ++m)
        bb4[m] = *(const float4*)((const float*)(ws + OFF_B1C) + m * 16 + hi * 4);

    // ---- phase 0: per-wave imu staging (wave w stages seg0+w's 384 B); no barrier
    if (lane < 24)
        gll16((const char*)imu + (size_t)(seg0 + wid) * 384 + lane * 16,
              imuL + wid * 384);
    asm volatile("s_waitcnt vmcnt(0)" ::: "memory");
    __builtin_amdgcn_sched_barrier(0);

    // ---- phase 1: conv1 via MFMA; im2col B-fragment built directly in registers.
    //      Lane (hi,lo) holds B[k=hi*8..+8)][l=lo] of its wave's seg (kq = hi).
    {
        const float* xb = (const float*)(imuL + wid * 384) + lo * 6;
        float v[8];
        if (hi == 0) {          // k=0..7: (i,t)=(0,0)(0,1)(0,2)(1,0)(1,1)(1,2)(2,0)(2,1)
            v[0] = lo > 0  ? xb[-6] : 0.f;
            v[1] = xb[0];
            v[2] = lo < 15 ? xb[6]  : 0.f;
            v[3] = lo > 0  ? xb[-5] : 0.f;
            v[4] = xb[1];
            v[5] = lo < 15 ? xb[7]  : 0.f;
            v[6] = lo > 0  ? xb[-4] : 0.f;
            v[7] = xb[2];
        } else if (hi == 1) {   // k=8..15: (2,2)(3,0)(3,1)(3,2)(4,0)(4,1)(4,2)(5,0)
            v[0] = lo < 15 ? xb[8]  : 0.f;
            v[1] = lo > 0  ? xb[-3] : 0.f;
            v[2] = xb[3];
            v[3] = lo < 15 ? xb[9]  : 0.f;
            v[4] = lo > 0  ? xb[-2] : 0.f;
            v[5] = xb[4];
            v[6] = lo < 15 ? xb[10] : 0.f;
            v[7] = lo > 0  ? xb[-1] : 0.f;
        } else if (hi == 2) {   // k=16,17: (5,1)(5,2); rest pad
            v[0] = xb[5];
            v[1] = lo < 15 ? xb[11] : 0.f;
            v[2] = v[3] = v[4] = v[5] = v[6] = v[7] = 0.f;
        } else {
            v[0] = v[1] = v[2] = v[3] = v[4] = v[5] = v[6] = v[7] = 0.f;
        }
        uint4 pkv;
        pkv.x = cvt_pk_bf16(v[0], v[1]);
        pkv.y = cvt_pk_bf16(v[2], v[3]);
        pkv.z = cvt_pk_bf16(v[4], v[5]);
        pkv.w = cvt_pk_bf16(v[6], v[7]);
        short8 bq = __builtin_bit_cast(short8, pkv);

        f32x4 acc1[4];
#pragma unroll
        for (int m = 0; m < 4; ++m) acc1[m] = f32x4{0.f, 0.f, 0.f, 0.f};
#pragma unroll
        for (int m = 0; m < 4; ++m)
            acc1[m] = __builtin_amdgcn_mfma_f32_16x16x32_bf16(a1p[m], bq, acc1[m], 0, 0, 0);
        // epilogue: bias + leaky -> bf16 -> act1 (row=(seg,l), col=cout)
#pragma unroll
        for (int m = 0; m < 4; ++m) {
            float y0 = leaky(acc1[m][0] + bb4[m].x);
            float y1 = leaky(acc1[m][1] + bb4[m].y);
            float y2 = leaky(acc1[m][2] + bb4[m].z);
            float y3 = leaky(acc1[m][3] + bb4[m].w);
            uint2 pk;
            pk.x = cvt_pk_bf16(y0, y1);
            pk.y = cvt_pk_bf16(y2, y3);
            *(uint2*)(act1L + (wid * 18 + lo + 1) * 144 + m * 32 + hi * 8) = pk;
        }
        // zero act1 halo rows (8 segs x 2 rows x 9 units = 144)
        if (tid < 144) {
            int s = tid / 18, rest = tid % 18;
            int h = rest / 9, unit = rest % 9;
            int4 z; z.x = z.y = z.z = z.w = 0;
            *(int4*)(act1L + (s * 18 + h * 17) * 144 + unit * 16) = z;
        }
        // zero act2 halo rows (8 x 2 x 17 = 272)
        if (tid < 272) {
            int s = tid / 34, rest = tid % 34;
            int h = rest / 17, unit = rest % 17;
            int4 z; z.x = z.y = z.z = z.w = 0;
            *(int4*)(act2L + (s * 18 + h * 17) * 272 + unit * 16) = z;
        }
    }

    // ---- conv2 FULL weight prefetch (all 6 ksteps, 12 frags = 48 VGPR) BEFORE B1;
    //      issued under conv1 epilogue, vmcnt survives the raw barrier.
    const int mi2 = wid >> 1, ni2 = wid & 1;
    short8 a2p[6][2];
#pragma unroll
    for (int s = 0; s < 6; ++s)
#pragma unroll
        for (int rt = 0; rt < 2; ++rt)
            a2p[s][rt] = frag16(A2F + (size_t)((s * 8 + mi2 * 2 + rt) * 64 + lane) * 16);

    sync_lds();                                // B1: act1 ready

    // ---- phase 2: conv2 16x16 (W as A from prefetched regs, act1 as B from LDS)
    //      wave (mi2, ni2): rows [mi2*32,+32), cols [ni2*64,+64) = segs ni2*4..+4
    f32x4 acc2[2][4];
#pragma unroll
    for (int i = 0; i < 2; ++i)
#pragma unroll
        for (int j = 0; j < 4; ++j) acc2[i][j] = f32x4{0.f, 0.f, 0.f, 0.f};
    {
        const char* b1base = act1L + lo * 144 + hi * 16;
#pragma unroll
        for (int s = 0; s < 6; ++s) {
            const int tap = s >> 1, qq = s & 1;
            short8 bfr[4];
#pragma unroll
            for (int ct = 0; ct < 4; ++ct)
                bfr[ct] = frag16(b1base + ((ni2 * 4 + ct) * 18 + tap) * 144 + qq * 64);
#pragma unroll
            for (int ct = 0; ct < 4; ++ct) {
                acc2[0][ct] = __builtin_amdgcn_mfma_f32_16x16x32_bf16(a2p[s][0], bfr[ct], acc2[0][ct], 0, 0, 0);
                acc2[1][ct] = __builtin_amdgcn_mfma_f32_16x16x32_bf16(a2p[s][1], bfr[ct], acc2[1][ct], 0, 0, 0);
            }
        }
    }

    // ---- conv3 weight+bias prefetch (s=0,1) issued BEFORE B2
    const int ni3 = wid >> 1, mi3 = wid & 1;
    short8 w3p[2][4];
#pragma unroll
    for (int s = 0; s < 2; ++s)
#pragma unroll
        for (int ct = 0; ct < 4; ++ct)
            w3p[s][ct] = frag16(A3F + (size_t)((s * 16 + ni3 * 4 + ct) * 64 + lane) * 16);
    float b3r[4];
#pragma unroll
    for (int ct = 0; ct < 4; ++ct)
        b3r[ct] = bias3[(ni3 * 4 + ct) * 16 + lo];

    // conv2 epilogue: bias + leaky -> bf16 -> act2 LDS (row=(seg,l), col=cout)
#pragma unroll
    for (int rt = 0; rt < 2; ++rt) {
        int ch0 = (mi2 * 2 + rt) * 16 + hi * 4;
        float4 b4 = *(const float4*)(bias2 + ch0);
#pragma unroll
        for (int ct = 0; ct < 4; ++ct) {
            float y0 = leaky(acc2[rt][ct][0] + b4.x);
            float y1 = leaky(acc2[rt][ct][1] + b4.y);
            float y2 = leaky(acc2[rt][ct][2] + b4.z);
            float y3 = leaky(acc2[rt][ct][3] + b4.w);
            uint2 pk;
            pk.x = cvt_pk_bf16(y0, y1);
            pk.y = cvt_pk_bf16(y2, y3);
            *(uint2*)(act2L + ((ni2 * 4 + ct) * 18 + lo + 1) * 272 + ch0 * 2) = pk;
        }
    }
    sync_lds();                                // B2: act2 ready

    // ---- phase 3: conv3 16x16 SWAPPED (act2 as A from LDS, W as B 2-deep regs)
    //      wave (ni3: couts [ni3*64,+64), mi3: segs [mi3*4,+4))
    f32x4 acc3[4][4];                          // [mt][ct]
#pragma unroll
    for (int i = 0; i < 4; ++i)
#pragma unroll
        for (int j = 0; j < 4; ++j) acc3[i][j] = f32x4{0.f, 0.f, 0.f, 0.f};
    {
#pragma unroll
        for (int s = 0; s < 12; ++s) {
            const int tap = s >> 2, ih = (s >> 1) & 1, qq = s & 1;
            short8 afr[4];
#pragma unroll
            for (int mt = 0; mt < 4; ++mt)
                afr[mt] = frag16(act2L + ((mi3 * 4 + mt) * 18 + lo + tap) * 272
                                 + ih * 128 + qq * 64 + hi * 16);
#pragma unroll
            for (int mt = 0; mt < 4; ++mt)
#pragma unroll
                for (int ct = 0; ct < 4; ++ct)
                    acc3[mt][ct] = __builtin_amdgcn_mfma_f32_16x16x32_bf16(
                        afr[mt], w3p[s & 1][ct], acc3[mt][ct], 0, 0, 0);
            if (s < 10) {
#pragma unroll
                for (int ct = 0; ct < 4; ++ct)
                    w3p[s & 1][ct] = frag16(A3F + (size_t)(((s + 2) * 16 + ni3 * 4 + ct) * 64 + lane) * 16);
            }
        }
    }

    // ---- phase 4: pool. C: row = l (hi*4+r), col = cout (lo).
    //      hi/lo bf16 planes via cvt_pk + residual-from-packed-bits trick.
#pragma unroll
    for (int ct = 0; ct < 4; ++ct) {
        int co = (ni3 * 4 + ct) * 16 + lo;
        float bv = b3r[ct];
        float t[4];
#pragma unroll
        for (int mt = 0; mt < 4; ++mt) {
            float s4 = 0.f;
#pragma unroll
            for (int r = 0; r < 4; ++r)
                s4 += leaky(acc3[mt][ct][r] + bv);
            s4 += __shfl_xor(s4, 16, 64);
            s4 += __shfl_xor(s4, 32, 64);
            t[mt] = s4;
        }
        unsigned int pkA = cvt_pk_bf16(t[0], t[1]);
        unsigned int pkB = cvt_pk_bf16(t[2], t[3]);
        float r0 = t[0] - asf(pkA << 16);
        float r1 = t[1] - asf(pkA & 0xffff0000u);
        float r2 = t[2] - asf(pkB << 16);
        float r3 = t[3] - asf(pkB & 0xffff0000u);
        unsigned int pkrA = cvt_pk_bf16(r0, r1);
        unsigned int pkrB = cvt_pk_bf16(r2, r3);
        if (hi == 0) {
            int row0 = mi3 * 4;
            char* pc = poolsL + co * 2;
            *(unsigned short*)(pc + (row0 + 0) * 528) = (unsigned short)pkA;
            *(unsigned short*)(pc + (row0 + 1) * 528) = (unsigned short)(pkA >> 16);
            *(unsigned short*)(pc + (row0 + 2) * 528) = (unsigned short)pkB;
            *(unsigned short*)(pc + (row0 + 3) * 528) = (unsigned short)(pkB >> 16);
            *(unsigned short*)(pc + (row0 + 8) * 528) = (unsigned short)pkrA;
            *(unsigned short*)(pc + (row0 + 9) * 528) = (unsigned short)(pkrA >> 16);
            *(unsigned short*)(pc + (row0 + 10) * 528) = (unsigned short)pkrB;
            *(unsigned short*)(pc + (row0 + 11) * 528) = (unsigned short)(pkrB >> 16);
        }
    }

    // ---- linear FULL weight+bias prefetch (16 frags = 64 VGPR; acc3 is dead now)
    short8 wbp[8][2];
#pragma unroll
    for (int q = 0; q < 8; ++q)
#pragma unroll
        for (int ct = 0; ct < 2; ++ct)
            wbp[q][ct] = frag16(WPF + (size_t)(((wid * 2 + ct) * 8 + q) * 64 + lane) * 16);
    float bpr[2];
#pragma unroll
    for (int ct = 0; ct < 2; ++ct)
        bpr[ct] = bp[(wid * 2 + ct) * 16 + lo];

    sync_lds();                                // B3: pools ready

    // ---- phase 5: linear (pools rows 0-7 hi, 8-15 lo as A; WP as B). out = C[s]+C[s+8].
    {
        f32x4 acc4[2];
        acc4[0] = f32x4{0.f, 0.f, 0.f, 0.f};
        acc4[1] = f32x4{0.f, 0.f, 0.f, 0.f};
#pragma unroll
        for (int q = 0; q < 8; ++q) {
            short8 pa = frag16(poolsL + lo * 528 + q * 64 + hi * 16);
            acc4[0] = __builtin_amdgcn_mfma_f32_16x16x32_bf16(pa, wbp[q][0], acc4[0], 0, 0, 0);
            acc4[1] = __builtin_amdgcn_mfma_f32_16x16x32_bf16(pa, wbp[q][1], acc4[1], 0, 0, 0);
        }
#pragma unroll
        for (int ct = 0; ct < 2; ++ct) {
            int o = (wid * 2 + ct) * 16 + lo;
            float bv = bpr[ct];
#pragma unroll
            for (int r = 0; r < 4; ++r) {
                float t = acc4[ct][r] + __shfl_xor(acc4[ct][r], 32, 64);
                if (hi < 2)
                    out[(size_t)(seg0 + hi * 4 + r) * 256 + o] = t + bv;
            }
        }
    }
}

}  // namespace

extern "C" void kernel_launch(void* const* d_in, const int* in_sizes, int n_in,
                              void* d_out, int out_size, void* d_ws, size_t ws_size,
                              hipStream_t stream) {
    if (ws_size < WS_NEED) return;

    const float* imu = (const float*)d_in[0];
    const float* w1 = (const float*)d_in[1];  const float* b1 = (const float*)d_in[2];
    const float* g1 = (const float*)d_in[3];  const float* be1 = (const float*)d_in[4];
    const float* m1 = (const float*)d_in[5];  const float* v1 = (const float*)d_in[6];
    const float* w2 = (const float*)d_in[7];  const float* b2 = (const float*)d_in[8];
    const float* g2 = (const float*)d_in[9];  const float* be2 = (const float*)d_in[10];
    const float* m2 = (const float*)d_in[11]; const float* v2 = (const float*)d_in[12];
    const float* w3 = (const float*)d_in[13]; const float* b3 = (const float*)d_in[14];
    const float* g3 = (const float*)d_in[15]; const float* be3 = (const float*)d_in[16];
    const float* m3 = (const float*)d_in[17]; const float* v3 = (const float*)d_in[18];
    const float* wp = (const float*)d_in[19]; const float* bp = (const float*)d_in[20];
    float* out = (float*)d_out;
    char* ws = (char*)d_ws;

    hipLaunchKernelGGL(k0_prep, dim3(95), dim3(256), 0, stream,
                       w1, b1, g1, be1, m1, v1,
                       w2, b2, g2, be2, m2, v2, w3, b3, g3, be3, m3, v3, wp, ws);
    hipLaunchKernelGGL(k_all, dim3(NSEG / 8), dim3(512), 0, stream,
                       imu, ws, bp, out);
}